// Round 2
// baseline (376.235 us; speedup 1.0000x reference)
//
#include <hip/hip_runtime.h>
#include <math.h>

#define B 256
#define D 512
#define S 196
#define NCH 8              // d-chunks for logits kernel
#define ROWS_PER_CH (D / NCH)       // 64
#define NPART 32           // NCH * 4 waves: partial-sum slots per batch

// ---------------- K1: p[b,d] = mem[b,d]*(u[b,:]@W[:,d]) + u[b,d], u = ctrl*w_attn
// b_concat dropped (softmax-shift-invariant). 4 batches per block to cut W
// L2 traffic 4x; grid = (B/4)*2 = 128 blocks x 256 threads.
__global__ __launch_bounds__(256) void k_prep(const float* __restrict__ mem,
                                              const float* __restrict__ ctrl,
                                              const float* __restrict__ W,
                                              const float* __restrict__ w_attn,
                                              float* __restrict__ p) {
    __shared__ float u_s[4][D];
    const int bg   = blockIdx.x >> 1;       // batch group (4 batches)
    const int half = blockIdx.x & 1;
    const int t    = threadIdx.x;
    const int d    = half * 256 + t;
    const int b0   = bg * 4;
    // load u for 4 batches: 4*512 = 2048 elems / 256 threads = 8 each
#pragma unroll
    for (int i = 0; i < 8; ++i) {
        int idx = i * 256 + t;              // [0, 2048)
        int j = idx >> 9, e = idx & 511;
        u_s[j][e] = ctrl[(b0 + j) * D + e] * w_attn[e];
    }
    __syncthreads();
    float a0 = 0.f, a1 = 0.f, a2 = 0.f, a3 = 0.f;
#pragma unroll 8
    for (int e = 0; e < D; ++e) {
        float wv = W[e * D + d];            // coalesced over t; W L2-resident
        a0 += u_s[0][e] * wv;
        a1 += u_s[1][e] * wv;
        a2 += u_s[2][e] * wv;
        a3 += u_s[3][e] * wv;
    }
    p[(b0 + 0) * D + d] = mem[(b0 + 0) * D + d] * a0 + u_s[0][d];
    p[(b0 + 1) * D + d] = mem[(b0 + 1) * D + d] * a1 + u_s[1][d];
    p[(b0 + 2) * D + d] = mem[(b0 + 2) * D + d] * a2 + u_s[2][d];
    p[(b0 + 3) * D + d] = mem[(b0 + 3) * D + d] * a3 + u_s[3][d];
}

// ---------------- K2: partial logits. Grid B*NCH blocks x 256 thr (4 waves).
// Wave w owns 16 rows of its 64-row chunk; lanes 0-48 read one full 784B row
// per float4 instruction; per-lane acc4 covers s = 4*lane..4*lane+3.
// Partials out: rai_part[b][chunk*4+w][s] (no atomics).
__global__ __launch_bounds__(256) void k_logits(const float* __restrict__ kb,
                                                const float* __restrict__ p,
                                                float* __restrict__ rai_part) {
    __shared__ float p_s[ROWS_PER_CH];
    const int bid = blockIdx.x;
    const int b = bid >> 3, c = bid & 7;
    const int t = threadIdx.x;
    const int w = t >> 6, l = t & 63;
    const int d0 = c * ROWS_PER_CH;
    if (t < ROWS_PER_CH) p_s[t] = p[b * D + d0 + t];
    __syncthreads();

    const float* kbb = kb + (size_t)b * D * S + (size_t)d0 * S;
    float4 acc = make_float4(0.f, 0.f, 0.f, 0.f);
    if (l < 49) {
#pragma unroll
        for (int r = 0; r < 16; ++r) {
            const int row = w * 16 + r;
            const float4 v = *(const float4*)(kbb + row * S + l * 4);
            const float pv = p_s[row];
            acc.x += pv * v.x; acc.y += pv * v.y;
            acc.z += pv * v.z; acc.w += pv * v.w;
        }
        float4* dst = (float4*)(rai_part + ((size_t)b * NPART + c * 4 + w) * S);
        dst[l] = acc;
    }
}

// ---------------- K3: sum partials + softmax -> rvi[b][s]. Grid B x 256 thr.
__global__ __launch_bounds__(256) void k_softmax(const float* __restrict__ rai_part,
                                                 float* __restrict__ rvi) {
    __shared__ float red[8];
    const int b = blockIdx.x;
    const int t = threadIdx.x;
    const int lane = t & 63, wave = t >> 6;
    float rai = -INFINITY;
    if (t < S) {
        float v = 0.f;
        const float* src = rai_part + (size_t)b * NPART * S + t;
#pragma unroll
        for (int k = 0; k < NPART; ++k) v += src[k * S];
        rai = v;
    }
    float m = rai;
#pragma unroll
    for (int o = 1; o < 64; o <<= 1) m = fmaxf(m, __shfl_xor(m, o, 64));
    if (lane == 0) red[wave] = m;
    __syncthreads();
    m = fmaxf(fmaxf(red[0], red[1]), fmaxf(red[2], red[3]));
    float ex = (t < S) ? __expf(rai - m) : 0.f;
    float sum = ex;
#pragma unroll
    for (int o = 1; o < 64; o <<= 1) sum += __shfl_xor(sum, o, 64);
    if (lane == 0) red[4 + wave] = sum;
    __syncthreads();
    const float l = red[4] + red[5] + red[6] + red[7];
    if (t < S) rvi[b * S + t] = ex / l;
}

// ---------------- K4: out[b,e] = sum_s rvi[b,s]*kb[b,e,s]. One wave per row;
// lanes 0-48 load the whole 784B row in one float4 instr; shuffle-reduce.
// Grid = B*D/4 blocks x 256 thr (4 rows per block, same b).
__global__ __launch_bounds__(256) void k_wsum(const float* __restrict__ kb,
                                              const float* __restrict__ rvi,
                                              float* __restrict__ out) {
    __shared__ float rvi_s[S];
    const int t = threadIdx.x;
    const int w = t >> 6, l = t & 63;
    const int R0 = blockIdx.x * 4;          // first row of this block
    const int b = R0 >> 9;
    if (t < S) rvi_s[t] = rvi[b * S + t];
    __syncthreads();
    const int e = (R0 & 511) + w;
    float acc = 0.f;
    if (l < 49) {
        const float4 v = *(const float4*)(kb + ((size_t)b * D + e) * S + l * 4);
        acc = rvi_s[4 * l + 0] * v.x + rvi_s[4 * l + 1] * v.y +
              rvi_s[4 * l + 2] * v.z + rvi_s[4 * l + 3] * v.w;
    }
#pragma unroll
    for (int o = 1; o < 64; o <<= 1) acc += __shfl_xor(acc, o, 64);
    if (l == 0) out[(size_t)b * D + e] = acc;
}

extern "C" void kernel_launch(void* const* d_in, const int* in_sizes, int n_in,
                              void* d_out, int out_size, void* d_ws, size_t ws_size,
                              hipStream_t stream) {
    const float* mem  = (const float*)d_in[0];  // [B, d]
    const float* ctrl = (const float*)d_in[1];  // [B, d]
    const float* kb   = (const float*)d_in[2];  // [B, d, S]
    const float* W    = (const float*)d_in[3];  // [d, d]
    // d_in[4] = b_concat: softmax-invariant, unused
    const float* wat  = (const float*)d_in[5];  // [d]
    float* out = (float*)d_out;                 // [B, d]; doubles as p scratch

    float* rai_part = (float*)d_ws;                       // B*NPART*S floats = 6.4 MB
    float* rvi      = rai_part + (size_t)B * NPART * S;   // B*S floats

    k_prep   <<<128,          256, 0, stream>>>(mem, ctrl, W, wat, out);
    k_logits <<<B * NCH,      256, 0, stream>>>(kb, out, rai_part);
    k_softmax<<<B,            256, 0, stream>>>(rai_part, rvi);
    k_wsum   <<<B * D / 4,    256, 0, stream>>>(kb, rvi, out);
}

// Round 3
// 247.440 us; speedup vs baseline: 1.5205x; 1.5205x over previous
//
#include <hip/hip_runtime.h>
#include <math.h>

#define B 256
#define D 512
#define S 196
#define SQ 49   // float4 quads per 196-float row

// ---------------- K1: p[b,d] = mem[b,d]*(u[b,:]@W[:,d]) + u[b,d], u = ctrl*w_attn
// b_concat dropped (softmax shift-invariant). 64 blocks x 512 threads, 4 batches
// per block. Thread t: d-quad q = t&127, e-chunk c = t>>7 (128 e's each) ->
// 128 float4 W loads per thread, 8 in flight (unroll 8), LDS partial reduce.
__global__ __launch_bounds__(512) void k_prep(const float* __restrict__ mem,
                                              const float* __restrict__ ctrl,
                                              const float* __restrict__ W,
                                              const float* __restrict__ w_attn,
                                              float* __restrict__ p) {
    __shared__ float u_s[4][D];          // 8 KB
    __shared__ float4 pp[4][4][128];     // [e-chunk][batch][quad], 32 KB
    const int t = threadIdx.x;
    const int b0 = blockIdx.x * 4;
#pragma unroll
    for (int i = 0; i < 4; ++i) {
        int idx = i * 512 + t;
        int j = idx >> 9, e = idx & 511;
        u_s[j][e] = ctrl[(b0 + j) * D + e] * w_attn[e];
    }
    __syncthreads();
    const int q = t & 127, c = t >> 7;
    const float4* W4 = (const float4*)W;  // W4[e*128 + q] = W[e][4q..4q+3]
    float4 a0 = {0,0,0,0}, a1 = {0,0,0,0}, a2 = {0,0,0,0}, a3 = {0,0,0,0};
#pragma unroll 8
    for (int i = 0; i < 128; ++i) {
        const int e = c * 128 + i;
        const float4 wv = W4[e * 128 + q];
        const float u0 = u_s[0][e], u1 = u_s[1][e], u2 = u_s[2][e], u3 = u_s[3][e];
        a0.x += u0 * wv.x; a0.y += u0 * wv.y; a0.z += u0 * wv.z; a0.w += u0 * wv.w;
        a1.x += u1 * wv.x; a1.y += u1 * wv.y; a1.z += u1 * wv.z; a1.w += u1 * wv.w;
        a2.x += u2 * wv.x; a2.y += u2 * wv.y; a2.z += u2 * wv.z; a2.w += u2 * wv.w;
        a3.x += u3 * wv.x; a3.y += u3 * wv.y; a3.z += u3 * wv.z; a3.w += u3 * wv.w;
    }
    pp[c][0][q] = a0; pp[c][1][q] = a1; pp[c][2][q] = a2; pp[c][3][q] = a3;
    __syncthreads();
    if (t < 128) {
#pragma unroll
        for (int j = 0; j < 4; ++j) {
            float4 s0 = pp[0][j][t], s1 = pp[1][j][t], s2 = pp[2][j][t], s3 = pp[3][j][t];
            float4 sm = {s0.x + s1.x + s2.x + s3.x, s0.y + s1.y + s2.y + s3.y,
                         s0.z + s1.z + s2.z + s3.z, s0.w + s1.w + s2.w + s3.w};
            const float4 m4 = ((const float4*)mem)[(b0 + j) * 128 + t];
            const float4 u4 = ((const float4*)&u_s[j][0])[t];
            float4 o;
            o.x = m4.x * sm.x + u4.x; o.y = m4.y * sm.y + u4.y;
            o.z = m4.z * sm.z + u4.z; o.w = m4.w * sm.w + u4.w;
            ((float4*)p)[(b0 + j) * 128 + t] = o;
        }
    }
}

// ---------------- K2: fused logits + softmax + weighted sum. One block per b,
// 512 threads = 8 waves. Pass1: wave w streams rows w*64..w*64+63 (784B
// coalesced float4 row per instruction, lanes 0-48), acc4 per lane over
// s=4l..4l+3; LDS partial reduce over waves; block softmax; Pass2: wave w
// re-reads rows (L2/L3-hot), dot with rvi quad, 6-shuffle reduce, lane0 store.
__global__ __launch_bounds__(512) void k_fused(const float* __restrict__ kb,
                                               const float* __restrict__ p,
                                               float* __restrict__ out) {
    __shared__ float p_s[D];
    __shared__ float part[8 * S];   // per-wave logit partials
    __shared__ float rvi_s[S];
    __shared__ float redm[8], reds[8];
    const int b = blockIdx.x;
    const int t = threadIdx.x;
    const int w = t >> 6, l = t & 63;
    p_s[t] = p[b * D + t];
    __syncthreads();
    const float* kbb = kb + (size_t)b * D * S;

    // ---- pass 1: logits ----
    float4 acc = {0.f, 0.f, 0.f, 0.f};
    if (l < SQ) {
#pragma unroll 8
        for (int k = 0; k < 64; ++k) {
            const int row = w * 64 + k;
            const float4 v = *(const float4*)(kbb + (size_t)row * S + 4 * l);
            const float pv = p_s[row];
            acc.x += pv * v.x; acc.y += pv * v.y;
            acc.z += pv * v.z; acc.w += pv * v.w;
        }
        *(float4*)&part[w * S + 4 * l] = acc;
    }
    __syncthreads();

    // ---- softmax over s (thread t -> s = t, t < 196) ----
    float rai = -INFINITY;
    if (t < S) {
        float v = 0.f;
#pragma unroll
        for (int ww = 0; ww < 8; ++ww) v += part[ww * S + t];
        rai = v;
    }
    float m = rai;
#pragma unroll
    for (int o = 1; o < 64; o <<= 1) m = fmaxf(m, __shfl_xor(m, o, 64));
    if (l == 0) redm[w] = m;
    __syncthreads();
    m = redm[0];
#pragma unroll
    for (int ww = 1; ww < 8; ++ww) m = fmaxf(m, redm[ww]);
    float ex = (t < S) ? __expf(rai - m) : 0.f;
    float sm = ex;
#pragma unroll
    for (int o = 1; o < 64; o <<= 1) sm += __shfl_xor(sm, o, 64);
    if (l == 0) reds[w] = sm;
    __syncthreads();
    float li = 0.f;
#pragma unroll
    for (int ww = 0; ww < 8; ++ww) li += reds[ww];
    if (t < S) rvi_s[t] = ex / li;
    __syncthreads();

    // ---- pass 2: out[b,e] = sum_s rvi[s]*kb[b,e,s]; wave w -> rows w*64+k ----
    float4 rv = {0.f, 0.f, 0.f, 0.f};
    if (l < SQ) rv = *(const float4*)&rvi_s[4 * l];
#pragma unroll 4
    for (int k = 0; k < 64; ++k) {
        const int e = w * 64 + k;
        float a = 0.f;
        if (l < SQ) {
            const float4 v = *(const float4*)(kbb + (size_t)e * S + 4 * l);
            a = rv.x * v.x + rv.y * v.y + rv.z * v.z + rv.w * v.w;
        }
#pragma unroll
        for (int o = 1; o < 64; o <<= 1) a += __shfl_xor(a, o, 64);
        if (l == 0) out[b * D + e] = a;
    }
}

extern "C" void kernel_launch(void* const* d_in, const int* in_sizes, int n_in,
                              void* d_out, int out_size, void* d_ws, size_t ws_size,
                              hipStream_t stream) {
    const float* mem  = (const float*)d_in[0];  // [B, d]
    const float* ctrl = (const float*)d_in[1];  // [B, d]
    const float* kb   = (const float*)d_in[2];  // [B, d, S]
    const float* W    = (const float*)d_in[3];  // [d, d]
    // d_in[4] = b_concat: softmax-invariant, unused
    const float* wat  = (const float*)d_in[5];  // [d]
    float* out = (float*)d_out;                 // [B, d]
    float* pbuf = (float*)d_ws;                 // [B, d] scratch in ws

    k_prep <<<B / 4, 512, 0, stream>>>(mem, ctrl, W, wat, pbuf);
    k_fused<<<B,     512, 0, stream>>>(kb, pbuf, out);
}

// Round 4
// 198.018 us; speedup vs baseline: 1.9000x; 1.2496x over previous
//
#include <hip/hip_runtime.h>
#include <math.h>

#define B 256
#define D 512
#define S 196
#define SQ 49   // float4 quads per 196-float row

// Single fused kernel: one block per batch, 512 threads = 8 waves.
// rai[b,s] = sum_d kb[b,d,s] * p[b,d],  p = mem*(u@W) + u,  u = ctrl*w_attn
// (b_concat term is softmax-shift-invariant -> dropped)
// out[b,d] = sum_s softmax(rai)[s] * kb[b,d,s]
//
// __launch_bounds__(512, 2): grid==256==CU count, so 1 block/CU (8 waves) is
// the occupancy ceiling anyway; the ,2 lifts the VGPR cap to 256 so the
// explicit 8-16 deep load batches below actually stay in flight (R3's
// VGPR=32 allocation serialized every load -> 1.4 TB/s).
__global__ __launch_bounds__(512, 2) void k_all(const float* __restrict__ mem,
                                                const float* __restrict__ ctrl,
                                                const float* __restrict__ W,
                                                const float* __restrict__ w_attn,
                                                const float* __restrict__ kb,
                                                float* __restrict__ out) {
    __shared__ float u_s[D];
    __shared__ float p_s[D];
    __shared__ float part[8 * S];   // per-wave logit partials
    __shared__ float rvi_s[S];
    __shared__ float o_s[D];
    __shared__ float redm[8], reds[8];
    const int b = blockIdx.x;
    const int t = threadIdx.x;
    const int w = t >> 6, l = t & 63;

    // ---- phase 0: u = ctrl * w_attn ----
    u_s[t] = ctrl[b * D + t] * w_attn[t];
    __syncthreads();

    // ---- phase 1: p[t] = mem[b,t]*(sum_e u[e]*W[e,t]) + u[t] ----
    // thread t owns column t of W: W[e*D+t] coalesced across t; 16 loads
    // batched into registers before the FMAs -> 16 outstanding L2 loads.
    {
        float acc = 0.f;
        for (int e0 = 0; e0 < D; e0 += 16) {
            float wv[16];
#pragma unroll
            for (int i = 0; i < 16; ++i) wv[i] = W[(e0 + i) * D + t];
#pragma unroll
            for (int i = 0; i < 16; ++i) acc += u_s[e0 + i] * wv[i];
        }
        p_s[t] = mem[b * D + t] * acc + u_s[t];
    }
    __syncthreads();

    const float* kbb = kb + (size_t)b * D * S;

    // ---- phase 2: logits. wave w streams rows w*64..w*64+63; lanes 0-48
    // cover one 784B row per load instruction; 8 rows in flight. ----
    if (l < SQ) {
        float4 acc = {0.f, 0.f, 0.f, 0.f};
#pragma unroll
        for (int k0 = 0; k0 < 64; k0 += 8) {
            float4 v[8];
#pragma unroll
            for (int i = 0; i < 8; ++i)
                v[i] = *(const float4*)(kbb + (size_t)(w * 64 + k0 + i) * S + 4 * l);
#pragma unroll
            for (int i = 0; i < 8; ++i) {
                const float pv = p_s[w * 64 + k0 + i];
                acc.x += pv * v[i].x; acc.y += pv * v[i].y;
                acc.z += pv * v[i].z; acc.w += pv * v[i].w;
            }
        }
        *(float4*)&part[w * S + 4 * l] = acc;
    }
    __syncthreads();

    // ---- phase 3: softmax over s (thread t -> s=t) ----
    float rai = -INFINITY;
    if (t < S) {
        float v = 0.f;
#pragma unroll
        for (int ww = 0; ww < 8; ++ww) v += part[ww * S + t];
        rai = v;
    }
    float m = rai;
#pragma unroll
    for (int o = 1; o < 64; o <<= 1) m = fmaxf(m, __shfl_xor(m, o, 64));
    if (l == 0) redm[w] = m;
    __syncthreads();
    m = redm[0];
#pragma unroll
    for (int ww = 1; ww < 8; ++ww) m = fmaxf(m, redm[ww]);
    float ex = (t < S) ? __expf(rai - m) : 0.f;
    float sm = ex;
#pragma unroll
    for (int o = 1; o < 64; o <<= 1) sm += __shfl_xor(sm, o, 64);
    if (l == 0) reds[w] = sm;
    __syncthreads();
    float li = 0.f;
#pragma unroll
    for (int ww = 0; ww < 8; ++ww) li += reds[ww];
    if (t < S) rvi_s[t] = ex / li;
    __syncthreads();

    // ---- phase 4: out[b,e] = sum_s rvi[s]*kb[b,e,s]; wave per row, rows
    // re-read L2/L3-hot, 8 in flight; shuffle-reduce; gather in LDS. ----
    float4 rv = {0.f, 0.f, 0.f, 0.f};
    if (l < SQ) rv = *(const float4*)&rvi_s[4 * l];
#pragma unroll
    for (int k0 = 0; k0 < 64; k0 += 8) {
        float a[8];
#pragma unroll
        for (int i = 0; i < 8; ++i) a[i] = 0.f;
        if (l < SQ) {
            float4 v[8];
#pragma unroll
            for (int i = 0; i < 8; ++i)
                v[i] = *(const float4*)(kbb + (size_t)(w * 64 + k0 + i) * S + 4 * l);
#pragma unroll
            for (int i = 0; i < 8; ++i)
                a[i] = rv.x * v[i].x + rv.y * v[i].y + rv.z * v[i].z + rv.w * v[i].w;
        }
#pragma unroll
        for (int i = 0; i < 8; ++i) {
#pragma unroll
            for (int o = 1; o < 64; o <<= 1) a[i] += __shfl_xor(a[i], o, 64);
            if (l == 0) o_s[w * 64 + k0 + i] = a[i];
        }
    }
    __syncthreads();
    if (t < 128) ((float4*)out)[(size_t)b * 128 + t] = ((const float4*)o_s)[t];
}

extern "C" void kernel_launch(void* const* d_in, const int* in_sizes, int n_in,
                              void* d_out, int out_size, void* d_ws, size_t ws_size,
                              hipStream_t stream) {
    const float* mem  = (const float*)d_in[0];  // [B, d]
    const float* ctrl = (const float*)d_in[1];  // [B, d]
    const float* kb   = (const float*)d_in[2];  // [B, d, S]
    const float* W    = (const float*)d_in[3];  // [d, d]
    // d_in[4] = b_concat: softmax-invariant, unused
    const float* wat  = (const float*)d_in[5];  // [d]
    float* out = (float*)d_out;                 // [B, d]

    k_all<<<B, 512, 0, stream>>>(mem, ctrl, W, wat, kb, out);
}

// Round 5
// 194.305 us; speedup vs baseline: 1.9363x; 1.0191x over previous
//
#include <hip/hip_runtime.h>
#include <math.h>

#define B 256
#define D 512
#define S 196
#define SQ 49    // float4 quads per 196-float row
#define NCH 8
#define CH 64

// Max-occupancy design: all kernels 256 thr (4 waves), tiny VGPR/LDS, many
// blocks -> 8 blocks/CU resident = 32 waves/CU. MLP comes from wave count
// (25 KB in flight/CU at 1 outstanding load/lane), not from compiler ILP
// (which collapsed every explicit batch in R2-R4; VGPR_Count stuck at 32).

// K1a: gpart[(b*8+c)*D + d] = sum_{e in chunk c} u[b,e]*W[e,d], u=ctrl*w_attn
__global__ __launch_bounds__(256) void k_gemm_part(const float* __restrict__ ctrl,
                                                   const float* __restrict__ w_attn,
                                                   const float* __restrict__ W,
                                                   float* __restrict__ gpart) {
    __shared__ float u_s[CH];
    const int bid = blockIdx.x;          // b*8 + c
    const int b = bid >> 3, c = bid & 7;
    const int t = threadIdx.x;
    if (t < CH) {
        const int e = c * CH + t;
        u_s[t] = ctrl[b * D + e] * w_attn[e];
    }
    __syncthreads();
    float a0 = 0.f, a1 = 0.f;
    for (int i = 0; i < CH; ++i) {
        const int e = c * CH + i;
        a0 += u_s[i] * W[e * D + t];          // coalesced; W L2-resident (1MB)
        a1 += u_s[i] * W[e * D + t + 256];
    }
    gpart[(size_t)bid * D + t]       = a0;
    gpart[(size_t)bid * D + t + 256] = a1;
}

// K1b: p[b,d] = mem[b,d]*sum_c gpart[b,c,d] + u[b,d]
// (b_concat dropped: softmax-shift-invariant)
__global__ __launch_bounds__(256) void k_prep2(const float* __restrict__ gpart,
                                               const float* __restrict__ mem,
                                               const float* __restrict__ ctrl,
                                               const float* __restrict__ w_attn,
                                               float* __restrict__ p) {
    const int idx = blockIdx.x * 256 + threadIdx.x;   // = b*D + d, grid 512
    const int d = idx & 511;
    float s = 0.f;
#pragma unroll
    for (int c = 0; c < NCH; ++c)
        s += gpart[((size_t)(idx >> 9) * NCH + c) * D + d];
    p[idx] = mem[idx] * s + ctrl[idx] * w_attn[d];
}

// K2: partial logits. Grid B*8 = 2048 blocks x 256 thr. Block (b,c) streams
// 64 rows of kb[b]; wave w: 16 rows, lanes 0-48 cover one 784B row per
// float4 load. In-block reduce over 4 waves -> rai_part[b*8+c][s].
__global__ __launch_bounds__(256) void k_logits(const float* __restrict__ kb,
                                                const float* __restrict__ p,
                                                float* __restrict__ rai_part) {
    __shared__ float p_s[CH];
    __shared__ float part[4][S];
    const int bid = blockIdx.x;
    const int b = bid >> 3, c = bid & 7;
    const int t = threadIdx.x;
    const int w = t >> 6, l = t & 63;
    if (t < CH) p_s[t] = p[b * D + c * CH + t];
    __syncthreads();
    const float* base = kb + (size_t)b * D * S + (size_t)c * CH * S;
    if (l < SQ) {
        float4 acc = {0.f, 0.f, 0.f, 0.f};
        for (int i = 0; i < 16; ++i) {
            const int r = w * 16 + i;
            const float4 v = *(const float4*)(base + (size_t)r * S + 4 * l);
            const float pv = p_s[r];
            acc.x += pv * v.x; acc.y += pv * v.y;
            acc.z += pv * v.z; acc.w += pv * v.w;
        }
        *(float4*)&part[w][4 * l] = acc;
    }
    __syncthreads();
    if (t < S)
        rai_part[(size_t)bid * S + t] = (part[0][t] + part[1][t]) + (part[2][t] + part[3][t]);
}

// K3: rai = sum of 8 partials; softmax over s -> rvi[b][s]. Grid B x 256.
__global__ __launch_bounds__(256) void k_softmax(const float* __restrict__ rai_part,
                                                 float* __restrict__ rvi) {
    __shared__ float redm[4], reds[4];
    const int b = blockIdx.x;
    const int t = threadIdx.x, w = t >> 6, l = t & 63;
    float rai = -INFINITY;
    if (t < S) {
        float v = 0.f;
#pragma unroll
        for (int c = 0; c < NCH; ++c)
            v += rai_part[((size_t)b * NCH + c) * S + t];
        rai = v;
    }
    float m = rai;
#pragma unroll
    for (int o = 1; o < 64; o <<= 1) m = fmaxf(m, __shfl_xor(m, o, 64));
    if (l == 0) redm[w] = m;
    __syncthreads();
    m = fmaxf(fmaxf(redm[0], redm[1]), fmaxf(redm[2], redm[3]));
    float ex = (t < S) ? __expf(rai - m) : 0.f;
    float sm = ex;
#pragma unroll
    for (int o = 1; o < 64; o <<= 1) sm += __shfl_xor(sm, o, 64);
    if (l == 0) reds[w] = sm;
    __syncthreads();
    const float li = (reds[0] + reds[1]) + (reds[2] + reds[3]);
    if (t < S) rvi[b * S + t] = ex / li;
}

// K4: out[b,e] = sum_s rvi[b,s]*kb[b,e,s]. Grid B*D/16 = 8192 blocks x 256.
// Wave w: 4 rows, one float4 row-load per row, 6-shuffle reduce. kb re-read
// is L3-resident (103 MB < 256 MB).
__global__ __launch_bounds__(256) void k_wsum(const float* __restrict__ kb,
                                              const float* __restrict__ rvi,
                                              float* __restrict__ out) {
    __shared__ float rvi_s[S];
    const int bid = blockIdx.x;
    const int b = bid >> 5, r0 = (bid & 31) * 16;
    const int t = threadIdx.x, w = t >> 6, l = t & 63;
    if (t < S) rvi_s[t] = rvi[b * S + t];
    __syncthreads();
    float4 rv = {0.f, 0.f, 0.f, 0.f};
    if (l < SQ) rv = *(const float4*)&rvi_s[4 * l];
#pragma unroll
    for (int i = 0; i < 4; ++i) {
        const int e = r0 + w * 4 + i;
        float a = 0.f;
        if (l < SQ) {
            const float4 v = *(const float4*)(kb + ((size_t)b * D + e) * S + 4 * l);
            a = rv.x * v.x + rv.y * v.y + rv.z * v.z + rv.w * v.w;
        }
#pragma unroll
        for (int o = 1; o < 64; o <<= 1) a += __shfl_xor(a, o, 64);
        if (l == 0) out[b * D + e] = a;
    }
}

extern "C" void kernel_launch(void* const* d_in, const int* in_sizes, int n_in,
                              void* d_out, int out_size, void* d_ws, size_t ws_size,
                              hipStream_t stream) {
    const float* mem  = (const float*)d_in[0];  // [B, d]
    const float* ctrl = (const float*)d_in[1];  // [B, d]
    const float* kb   = (const float*)d_in[2];  // [B, d, S]
    const float* W    = (const float*)d_in[3];  // [d, d]
    // d_in[4] = b_concat: softmax-invariant, unused
    const float* wat  = (const float*)d_in[5];  // [d]
    float* out = (float*)d_out;                 // [B, d]

    float* gpart    = (float*)d_ws;                         // B*8*D   = 4 MB
    float* p        = gpart + (size_t)B * NCH * D;          // B*D     = 512 KB
    float* rai_part = p + (size_t)B * D;                    // B*8*S   = 1.6 MB
    float* rvi      = rai_part + (size_t)B * NCH * S;       // B*S     = 200 KB

    k_gemm_part<<<B * NCH,     256, 0, stream>>>(ctrl, wat, W, gpart);
    k_prep2    <<<B * D / 256, 256, 0, stream>>>(gpart, mem, ctrl, wat, p);
    k_logits   <<<B * NCH,     256, 0, stream>>>(kb, p, rai_part);
    k_softmax  <<<B,           256, 0, stream>>>(rai_part, rvi);
    k_wsum     <<<B * D / 16,  256, 0, stream>>>(kb, rvi, out);
}

// Round 6
// 189.577 us; speedup vs baseline: 1.9846x; 1.0249x over previous
//
#include <hip/hip_runtime.h>
#include <math.h>

#define B 256
#define D 512
#define S 196
#define SQ 49    // float4 quads per 196-float row
#define NCH 8    // e-chunks / row-chunks of 64

// ---------------- K1: gpart[(b*8+ce)*D + d] = sum_{e in chunk ce} u[b,e]*W[e,d]
// u = ctrl*w_attn. Grid 256 blocks (ce 0..7 x b-octet 0..31) x 256 thr.
// Each W row is loaded ONCE per block and reused for 8 batches from registers
// -> W L2 traffic 32 MB (was 256 MB). 4-deep W-load batches for MLP.
__global__ __launch_bounds__(256) void k_gemm(const float* __restrict__ ctrl,
                                              const float* __restrict__ w_attn,
                                              const float* __restrict__ W,
                                              float* __restrict__ gpart) {
    __shared__ float u_s[64][8];         // [e_local][batch j] -> 32B rows
    const int ce = blockIdx.x >> 5;      // e-chunk
    const int b0 = (blockIdx.x & 31) * 8;
    const int t = threadIdx.x;
#pragma unroll
    for (int k = t; k < 512; k += 256) {
        const int j = k & 7, el = k >> 3;
        const int e = ce * 64 + el;
        u_s[el][j] = ctrl[(b0 + j) * D + e] * w_attn[e];
    }
    __syncthreads();
    float a0[8], a1[8];
#pragma unroll
    for (int j = 0; j < 8; ++j) { a0[j] = 0.f; a1[j] = 0.f; }
    for (int e0 = 0; e0 < 64; e0 += 4) {
        float w0[4], w1[4];
#pragma unroll
        for (int i = 0; i < 4; ++i) {
            const int e = ce * 64 + e0 + i;
            w0[i] = W[e * D + t];
            w1[i] = W[e * D + t + 256];
        }
#pragma unroll
        for (int i = 0; i < 4; ++i) {
            const float4 ua = *(const float4*)&u_s[e0 + i][0];
            const float4 ub = *(const float4*)&u_s[e0 + i][4];
            a0[0] += ua.x * w0[i]; a0[1] += ua.y * w0[i];
            a0[2] += ua.z * w0[i]; a0[3] += ua.w * w0[i];
            a0[4] += ub.x * w0[i]; a0[5] += ub.y * w0[i];
            a0[6] += ub.z * w0[i]; a0[7] += ub.w * w0[i];
            a1[0] += ua.x * w1[i]; a1[1] += ua.y * w1[i];
            a1[2] += ua.z * w1[i]; a1[3] += ua.w * w1[i];
            a1[4] += ub.x * w1[i]; a1[5] += ub.y * w1[i];
            a1[6] += ub.z * w1[i]; a1[7] += ub.w * w1[i];
        }
    }
#pragma unroll
    for (int j = 0; j < 8; ++j) {
        gpart[((size_t)(b0 + j) * NCH + ce) * D + t]       = a0[j];
        gpart[((size_t)(b0 + j) * NCH + ce) * D + t + 256] = a1[j];
    }
}

// ---------------- K2: p-head + partial logits. Grid B*8 = 2048 blocks x 256.
// Head: p_s[d] = mem*sum_ce(gpart) + u for this block's 64 d's (b_concat is
// softmax-shift-invariant -> dropped). Body: wave w streams 16 rows as TWO
// independent chains (2 outstanding 784B row loads per wave -> 50KB/CU in
// flight at 8 blocks/CU, > the ~22KB Little's-law HBM requirement).
__global__ __launch_bounds__(256) void k_logits(const float* __restrict__ kb,
                                                const float* __restrict__ gpart,
                                                const float* __restrict__ mem,
                                                const float* __restrict__ ctrl,
                                                const float* __restrict__ w_attn,
                                                float* __restrict__ rai_part) {
    __shared__ float p_s[64];
    __shared__ float part[4][S];
    const int bid = blockIdx.x;
    const int b = bid >> 3, c = bid & 7;
    const int t = threadIdx.x;
    const int w = t >> 6, l = t & 63;
    if (t < 64) {
        const int d = c * 64 + t;
        float s = 0.f;
#pragma unroll
        for (int ce = 0; ce < NCH; ++ce)
            s += gpart[((size_t)b * NCH + ce) * D + d];
        p_s[t] = mem[b * D + d] * s + ctrl[b * D + d] * w_attn[d];
    }
    __syncthreads();
    const float* base = kb + (size_t)b * D * S + (size_t)c * 64 * S;
    if (l < SQ) {
        float4 acc0 = {0.f, 0.f, 0.f, 0.f}, acc1 = {0.f, 0.f, 0.f, 0.f};
        for (int i = 0; i < 8; ++i) {
            const int r0 = w * 16 + i, r1 = w * 16 + 8 + i;
            const float4 v0 = *(const float4*)(base + (size_t)r0 * S + 4 * l);
            const float4 v1 = *(const float4*)(base + (size_t)r1 * S + 4 * l);
            const float pv0 = p_s[r0], pv1 = p_s[r1];
            acc0.x += pv0 * v0.x; acc0.y += pv0 * v0.y;
            acc0.z += pv0 * v0.z; acc0.w += pv0 * v0.w;
            acc1.x += pv1 * v1.x; acc1.y += pv1 * v1.y;
            acc1.z += pv1 * v1.z; acc1.w += pv1 * v1.w;
        }
        part[w][4 * l + 0] = acc0.x + acc1.x;
        part[w][4 * l + 1] = acc0.y + acc1.y;
        part[w][4 * l + 2] = acc0.z + acc1.z;
        part[w][4 * l + 3] = acc0.w + acc1.w;
    }
    __syncthreads();
    if (t < S)
        rai_part[(size_t)bid * S + t] = (part[0][t] + part[1][t]) + (part[2][t] + part[3][t]);
}

// ---------------- K3: softmax-head + weighted sum. Grid B*8 = 2048 x 256.
// Head: every block of batch b redoes the (cheap, L2-hot) softmax from the 8
// rai partials -> rvi_s. Body: 64 rows, 2-deep chains, kb re-read is L3-hot.
__global__ __launch_bounds__(256) void k_wsum(const float* __restrict__ kb,
                                              const float* __restrict__ rai_part,
                                              float* __restrict__ out) {
    __shared__ float rvi_s[S];
    __shared__ float redm[4], reds[4];
    const int bid = blockIdx.x;
    const int b = bid >> 3, c = bid & 7;
    const int t = threadIdx.x;
    const int w = t >> 6, l = t & 63;
    float rai = -INFINITY;
    if (t < S) {
        float v = 0.f;
#pragma unroll
        for (int k = 0; k < NCH; ++k)
            v += rai_part[((size_t)b * NCH + k) * S + t];
        rai = v;
    }
    float m = rai;
#pragma unroll
    for (int o = 1; o < 64; o <<= 1) m = fmaxf(m, __shfl_xor(m, o, 64));
    if (l == 0) redm[w] = m;
    __syncthreads();
    m = fmaxf(fmaxf(redm[0], redm[1]), fmaxf(redm[2], redm[3]));
    float ex = (t < S) ? __expf(rai - m) : 0.f;
    float sm = ex;
#pragma unroll
    for (int o = 1; o < 64; o <<= 1) sm += __shfl_xor(sm, o, 64);
    if (l == 0) reds[w] = sm;
    __syncthreads();
    const float li = (reds[0] + reds[1]) + (reds[2] + reds[3]);
    if (t < S) rvi_s[t] = ex / li;
    __syncthreads();

    float4 rv = {0.f, 0.f, 0.f, 0.f};
    if (l < SQ) rv = *(const float4*)&rvi_s[4 * l];
    const float* base = kb + (size_t)b * D * S + (size_t)c * 64 * S;
#pragma unroll
    for (int i = 0; i < 8; ++i) {
        const int r0 = w * 16 + i, r1 = w * 16 + 8 + i;
        float a0 = 0.f, a1 = 0.f;
        if (l < SQ) {
            const float4 v0 = *(const float4*)(base + (size_t)r0 * S + 4 * l);
            const float4 v1 = *(const float4*)(base + (size_t)r1 * S + 4 * l);
            a0 = rv.x * v0.x + rv.y * v0.y + rv.z * v0.z + rv.w * v0.w;
            a1 = rv.x * v1.x + rv.y * v1.y + rv.z * v1.z + rv.w * v1.w;
        }
#pragma unroll
        for (int o = 1; o < 64; o <<= 1) {
            a0 += __shfl_xor(a0, o, 64);
            a1 += __shfl_xor(a1, o, 64);
        }
        if (l == 0) {
            out[(size_t)b * D + c * 64 + r0] = a0;
            out[(size_t)b * D + c * 64 + r1] = a1;
        }
    }
}

extern "C" void kernel_launch(void* const* d_in, const int* in_sizes, int n_in,
                              void* d_out, int out_size, void* d_ws, size_t ws_size,
                              hipStream_t stream) {
    const float* mem  = (const float*)d_in[0];  // [B, d]
    const float* ctrl = (const float*)d_in[1];  // [B, d]
    const float* kb   = (const float*)d_in[2];  // [B, d, S]
    const float* W    = (const float*)d_in[3];  // [d, d]
    // d_in[4] = b_concat: softmax-invariant, unused
    const float* wat  = (const float*)d_in[5];  // [d]
    float* out = (float*)d_out;                 // [B, d]

    float* gpart    = (float*)d_ws;                      // B*8*D = 4 MB
    float* rai_part = gpart + (size_t)B * NCH * D;       // 2048*S = 1.6 MB

    k_gemm  <<<256,     256, 0, stream>>>(ctrl, wat, W, gpart);
    k_logits<<<B * NCH, 256, 0, stream>>>(kb, gpart, mem, ctrl, wat, rai_part);
    k_wsum  <<<B * NCH, 256, 0, stream>>>(kb, rai_part, out);
}